// Round 1
// baseline (696.462 us; speedup 1.0000x reference)
//
#include <hip/hip_runtime.h>
#include <hip/hip_bf16.h>
#include <stdint.h>

// DecoderBlock: x + attn(LN1(x)) -> x2; x2 + FFN(LN2(x2))
// B=4, T=2048, HIDDEN=1024, HEADS=16, HEAD=64, DFF=4096
// Strategy: bf16 MFMA GEMMs (fp32 accum), fp32 residual/LN/softmax.
// Workspace budget: 136 MB (weights-bt 24MB, h 16MB, Q/K/V/Vt 64MB (reused for ff1), x2 32MB).

#define HID 1024
#define NH 16
#define HD 64
#define DFF 4096
#define BATCH 4
#define SEQ 2048
#define NTOK (BATCH*SEQ)   // 8192

typedef unsigned short u16;
typedef __attribute__((ext_vector_type(4))) float f32x4;
typedef __attribute__((ext_vector_type(8))) __bf16 bf16x8;

__device__ __forceinline__ u16 f2bf(float f) {
    unsigned int u = __float_as_uint(f);
    u = (u + 0x7fffu + ((u >> 16) & 1u)) >> 16;   // RNE
    return (u16)u;
}

__device__ __forceinline__ void gload_lds16(const void* g, void* lds) {
    __builtin_amdgcn_global_load_lds(
        (const __attribute__((address_space(1))) unsigned int*)(uintptr_t)g,
        (__attribute__((address_space(3))) unsigned int*)(uintptr_t)lds, 16, 0, 0);
}

// ---------------- LayerNorm: f32 in -> bf16 out ----------------
__global__ __launch_bounds__(256) void ln_kernel(const float* __restrict__ x,
                                                 const float* __restrict__ g,
                                                 const float* __restrict__ be,
                                                 u16* __restrict__ out) {
    __shared__ float red[10];
    const int row = blockIdx.x, tid = threadIdx.x;
    const float4 v = ((const float4*)(x + (size_t)row * HID))[tid];
    float s  = v.x + v.y + v.z + v.w;
    float s2 = v.x*v.x + v.y*v.y + v.z*v.z + v.w*v.w;
    for (int off = 32; off > 0; off >>= 1) {
        s  += __shfl_down(s, off, 64);
        s2 += __shfl_down(s2, off, 64);
    }
    if ((tid & 63) == 0) { red[tid >> 6] = s; red[4 + (tid >> 6)] = s2; }
    __syncthreads();
    if (tid == 0) {
        red[8] = red[0] + red[1] + red[2] + red[3];
        red[9] = red[4] + red[5] + red[6] + red[7];
    }
    __syncthreads();
    const float mu  = red[8] * (1.f / HID);
    const float var = red[9] * (1.f / HID) - mu * mu;
    const float rstd = rsqrtf(var + 1e-5f);
    const float4 g4 = ((const float4*)g)[tid];
    const float4 b4 = ((const float4*)be)[tid];
    ushort4 o;
    o.x = f2bf((v.x - mu) * rstd * g4.x + b4.x);
    o.y = f2bf((v.y - mu) * rstd * g4.y + b4.y);
    o.z = f2bf((v.z - mu) * rstd * g4.z + b4.z);
    o.w = f2bf((v.w - mu) * rstd * g4.w + b4.w);
    ((ushort4*)(out + (size_t)row * HID))[tid] = o;
}

// ---------------- weight transpose+cast: out[c][r] = (bf16)in[r][c], batched ----------------
__global__ __launch_bounds__(256) void transpose_w(const float* __restrict__ in,
                                                   u16* __restrict__ out, int R, int C) {
    __shared__ float t[32][33];
    const int r0 = blockIdx.x * 32, c0 = blockIdx.y * 32;
    const float* inb = in + (size_t)blockIdx.z * R * C;
    u16* outb = out + (size_t)blockIdx.z * R * C;
    const int tid = threadIdx.x;
    const int tr = tid >> 3, tc = (tid & 7) * 4;
    const float4 v = *(const float4*)&inb[(size_t)(r0 + tr) * C + c0 + tc];
    t[tr][tc] = v.x; t[tr][tc + 1] = v.y; t[tr][tc + 2] = v.z; t[tr][tc + 3] = v.w;
    __syncthreads();
    ushort4 o;
    o.x = f2bf(t[tc + 0][tr]);
    o.y = f2bf(t[tc + 1][tr]);
    o.z = f2bf(t[tc + 2][tr]);
    o.w = f2bf(t[tc + 3][tr]);
    *(ushort4*)&outb[(size_t)(c0 + tr) * R + r0 + tc] = o;
}

// ---------------- V transpose (bf16): [bh][T][64] -> [bh][64][T] ----------------
__global__ __launch_bounds__(256) void transpose_v(const u16* __restrict__ in,
                                                   u16* __restrict__ out) {
    __shared__ u16 t[64][65];
    const int s0 = blockIdx.x * 64;
    const size_t bh = blockIdx.y;
    const u16* inb = in + bh * SEQ * HD;
    u16* outb = out + bh * HD * SEQ;
    const int tid = threadIdx.x;
    const int r = tid >> 2, c = (tid & 3) * 16;
    bf16x8 a = *(const bf16x8*)&inb[(size_t)(s0 + r) * HD + c];
    bf16x8 b = *(const bf16x8*)&inb[(size_t)(s0 + r) * HD + c + 8];
    #pragma unroll
    for (int i = 0; i < 8; i++) {
        t[r][c + i]     = ((const u16*)&a)[i];
        t[r][c + 8 + i] = ((const u16*)&b)[i];
    }
    __syncthreads();
    u16 o0[8], o1[8];
    #pragma unroll
    for (int i = 0; i < 8; i++) { o0[i] = t[c + i][r]; o1[i] = t[c + 8 + i][r]; }
    *(bf16x8*)&outb[(size_t)r * SEQ + s0 + c]     = *(const bf16x8*)o0;
    *(bf16x8*)&outb[(size_t)r * SEQ + s0 + c + 8] = *(const bf16x8*)o1;
}

// ---------------- GEMM: C[M][N] = A[M][K](bf16,rowmajor) * B^T[N][K](bf16,rowmajor) ----------------
// 128x128 tile, BK=32, 4 waves (2x2 of 64x64), 16x16x32 MFMA, global_load_lds staging (m97 structure).
// MODE 0: QKV scatter  -> outh[((b*16+h)*T + t)*64 + d] = bf16(acc*scale)
// MODE 1: f32 residual -> outf[r*N+c] = resid[r*N+c] + acc + bias[c]
// MODE 2: ReLU bf16    -> outh[r*N+c] = bf16(max(acc+bias[c],0))
template <int MODE>
__global__ __launch_bounds__(256) void gemm_kernel(const u16* __restrict__ A,
                                                   const u16* __restrict__ B,
                                                   float* __restrict__ outf,
                                                   u16* __restrict__ outh,
                                                   const float* __restrict__ bias,
                                                   const float* __restrict__ resid,
                                                   int K, int N, float scale) {
    __shared__ u16 Al[128][32];
    __shared__ u16 Bl[128][32];
    const int tid = threadIdx.x;
    const int w = tid >> 6, l = tid & 63;
    const int wr = w >> 1, wc = w & 1;
    const int m0 = blockIdx.x * 128, n0 = blockIdx.y * 128;

    f32x4 acc[4][4] = {};

    const u16* Ag = A + (size_t)(m0 + w * 32) * K;
    const u16* Bg = B + (size_t)(n0 + w * 32) * K;
    const int lr = l >> 2;            // row within 16-row chunk
    const int lc = (l & 3) * 8;       // col (elements)

    for (int k0 = 0; k0 < K; k0 += 32) {
        __syncthreads();   // previous iteration's LDS reads done
        #pragma unroll
        for (int it = 0; it < 2; it++) {
            gload_lds16(Ag + (size_t)(it * 16 + lr) * K + k0 + lc, &Al[w * 32 + it * 16][0]);
            gload_lds16(Bg + (size_t)(it * 16 + lr) * K + k0 + lc, &Bl[w * 32 + it * 16][0]);
        }
        __syncthreads();   // staging visible (compiler drains vmcnt before barrier)
        bf16x8 af[4], bf[4];
        #pragma unroll
        for (int i = 0; i < 4; i++)
            af[i] = *(const bf16x8*)&Al[wr * 64 + i * 16 + (l & 15)][(l >> 4) * 8];
        #pragma unroll
        for (int i = 0; i < 4; i++)
            bf[i] = *(const bf16x8*)&Bl[wc * 64 + i * 16 + (l & 15)][(l >> 4) * 8];
        #pragma unroll
        for (int mi = 0; mi < 4; mi++)
            #pragma unroll
            for (int nj = 0; nj < 4; nj++)
                acc[mi][nj] = __builtin_amdgcn_mfma_f32_16x16x32_bf16(af[mi], bf[nj], acc[mi][nj], 0, 0, 0);
    }

    const int r00 = m0 + wr * 64 + ((l >> 4) << 2);
    const int c00 = n0 + wc * 64 + (l & 15);
    if (MODE == 0) {
        #pragma unroll
        for (int nj = 0; nj < 4; nj++) {
            const int c = c00 + nj * 16;
            const int h = c >> 6, d = c & 63;
            #pragma unroll
            for (int mi = 0; mi < 4; mi++)
                #pragma unroll
                for (int j = 0; j < 4; j++) {
                    const int r = r00 + mi * 16 + j;
                    const int b = r >> 11, t = r & (SEQ - 1);
                    outh[((size_t)(b * NH + h) * SEQ + t) * HD + d] = f2bf(acc[mi][nj][j] * scale);
                }
        }
    } else if (MODE == 1) {
        #pragma unroll
        for (int nj = 0; nj < 4; nj++) {
            const int c = c00 + nj * 16;
            const float bi = bias[c];
            #pragma unroll
            for (int mi = 0; mi < 4; mi++)
                #pragma unroll
                for (int j = 0; j < 4; j++) {
                    const int r = r00 + mi * 16 + j;
                    const size_t idx = (size_t)r * N + c;
                    outf[idx] = resid[idx] + acc[mi][nj][j] + bi;
                }
        }
    } else {
        #pragma unroll
        for (int nj = 0; nj < 4; nj++) {
            const int c = c00 + nj * 16;
            const float bi = bias[c];
            #pragma unroll
            for (int mi = 0; mi < 4; mi++)
                #pragma unroll
                for (int j = 0; j < 4; j++) {
                    const int r = r00 + mi * 16 + j;
                    const float v = acc[mi][nj][j] + bi;
                    outh[(size_t)r * N + c] = f2bf(v > 0.f ? v : 0.f);
                }
        }
    }
}

// ---------------- Flash attention (causal) ----------------
// grid (T/64, B*NH); 256 thr = 4 waves; wave w owns Q rows [qt*64+w*16, +16).
// K/V tiles 64x64 in LDS, XOR-swizzled ((row&7)<<4 on byte offset) against 128B-row bank conflicts.
__global__ __launch_bounds__(256) void attn_kernel(const u16* __restrict__ Q,
                                                   const u16* __restrict__ K,
                                                   const u16* __restrict__ Vt,
                                                   u16* __restrict__ O) {
    __shared__ u16 Kl[64 * 64];
    __shared__ u16 Vl[64 * 64];
    __shared__ u16 Pl[4][16 * 64];
    const int qt = blockIdx.x, bh = blockIdx.y;
    const int tid = threadIdx.x, w = tid >> 6, l = tid & 63;
    const int g = l >> 4, c16 = l & 15;

    const u16* Qg = Q + ((size_t)bh * SEQ + qt * 64 + w * 16) * HD;
    bf16x8 qf[2];
    qf[0] = *(const bf16x8*)&Qg[(size_t)c16 * HD + g * 8];
    qf[1] = *(const bf16x8*)&Qg[(size_t)c16 * HD + 32 + g * 8];

    f32x4 o[4] = {};
    float mrow[4], lrow[4];
    #pragma unroll
    for (int j = 0; j < 4; j++) { mrow[j] = -1e30f; lrow[j] = 0.f; }

    char* KlB = (char*)Kl;
    char* VlB = (char*)Vl;
    char* PlB = (char*)&Pl[w][0];

    for (int st = 0; st <= qt; ++st) {
        __syncthreads();
        {   // stage K and Vt tiles (reg->LDS with swizzle)
            const u16* Kg = K + ((size_t)bh * SEQ + st * 64) * HD;
            const u16* Vg = Vt + (size_t)bh * HD * SEQ + st * 64;
            #pragma unroll
            for (int it = 0; it < 2; it++) {
                const int idx = it * 256 + tid;         // 0..511
                const int r = idx >> 3;                 // tile row
                const int cb = (idx & 7) * 16;          // col byte
                bf16x8 kv = *(const bf16x8*)((const char*)Kg + (size_t)r * 128 + cb);
                *(bf16x8*)(KlB + r * 128 + (cb ^ ((r & 7) << 4))) = kv;
                bf16x8 vv = *(const bf16x8*)((const char*)Vg + (size_t)r * (SEQ * 2) + cb);
                *(bf16x8*)(VlB + r * 128 + (cb ^ ((r & 7) << 4))) = vv;
            }
        }
        __syncthreads();

        // S = Q K^T  (S frag n: cols n*16+c16, rows g*4+j)
        f32x4 s[4];
        #pragma unroll
        for (int n = 0; n < 4; n++) {
            const int row = n * 16 + c16;
            const char* base = KlB + row * 128;
            bf16x8 b0 = *(const bf16x8*)(base + ((g * 16) ^ ((row & 7) << 4)));
            bf16x8 b1 = *(const bf16x8*)(base + ((64 + g * 16) ^ ((row & 7) << 4)));
            f32x4 z = {};
            z = __builtin_amdgcn_mfma_f32_16x16x32_bf16(qf[0], b0, z, 0, 0, 0);
            s[n] = __builtin_amdgcn_mfma_f32_16x16x32_bf16(qf[1], b1, z, 0, 0, 0);
        }
        if (st == qt) {   // causal mask inside diagonal tile
            #pragma unroll
            for (int n = 0; n < 4; n++)
                #pragma unroll
                for (int j = 0; j < 4; j++) {
                    const int ql = w * 16 + g * 4 + j, sl = n * 16 + c16;
                    if (sl > ql) s[n][j] = -1e30f;
                }
        }
        // online softmax
        #pragma unroll
        for (int j = 0; j < 4; j++) {
            float mx = fmaxf(fmaxf(s[0][j], s[1][j]), fmaxf(s[2][j], s[3][j]));
            for (int off = 1; off < 16; off <<= 1) mx = fmaxf(mx, __shfl_xor(mx, off, 64));
            const float newm = fmaxf(mrow[j], mx);
            const float sc = __expf(mrow[j] - newm);
            mrow[j] = newm;
            float ps = 0.f;
            #pragma unroll
            for (int n = 0; n < 4; n++) {
                const float p = __expf(s[n][j] - newm);
                s[n][j] = p; ps += p;
            }
            for (int off = 1; off < 16; off <<= 1) ps += __shfl_xor(ps, off, 64);
            lrow[j] = lrow[j] * sc + ps;
            #pragma unroll
            for (int n = 0; n < 4; n++) o[n][j] *= sc;
        }
        // P -> per-wave LDS (bf16, swizzled), becomes PV A-operand
        #pragma unroll
        for (int n = 0; n < 4; n++)
            #pragma unroll
            for (int j = 0; j < 4; j++) {
                const int row = g * 4 + j;
                const int cb = (n * 16 + c16) * 2;
                *(u16*)(PlB + row * 128 + (cb ^ ((row & 7) << 4))) = f2bf(s[n][j]);
            }
        bf16x8 pa[2];
        #pragma unroll
        for (int kb = 0; kb < 2; kb++) {
            const int row = c16;
            pa[kb] = *(const bf16x8*)(PlB + row * 128 + ((kb * 64 + g * 16) ^ ((row & 7) << 4)));
        }
        #pragma unroll
        for (int n = 0; n < 4; n++) {
            const int row = n * 16 + c16;   // d
            const char* base = VlB + row * 128;
            bf16x8 v0 = *(const bf16x8*)(base + ((g * 16) ^ ((row & 7) << 4)));
            bf16x8 v1 = *(const bf16x8*)(base + ((64 + g * 16) ^ ((row & 7) << 4)));
            o[n] = __builtin_amdgcn_mfma_f32_16x16x32_bf16(pa[0], v0, o[n], 0, 0, 0);
            o[n] = __builtin_amdgcn_mfma_f32_16x16x32_bf16(pa[1], v1, o[n], 0, 0, 0);
        }
    }

    // epilogue: O /= l, store concat-head layout [b][t][h*64+d]
    const int b = bh >> 4, h = bh & 15;
    #pragma unroll
    for (int j = 0; j < 4; j++) {
        const float inv = 1.f / lrow[j];
        const int t = qt * 64 + w * 16 + g * 4 + j;
        #pragma unroll
        for (int n = 0; n < 4; n++)
            O[((size_t)b * SEQ + t) * HID + h * HD + n * 16 + c16] = f2bf(o[n][j] * inv);
    }
}

// ---------------- launch ----------------
extern "C" void kernel_launch(void* const* d_in, const int* in_sizes, int n_in,
                              void* d_out, int out_size, void* d_ws, size_t ws_size,
                              hipStream_t stream) {
    (void)in_sizes; (void)n_in; (void)out_size; (void)ws_size;
    const float* x   = (const float*)d_in[0];
    const float* Wq  = (const float*)d_in[1];
    const float* Wk  = (const float*)d_in[2];
    const float* Wv  = (const float*)d_in[3];
    const float* Wo  = (const float*)d_in[4];
    const float* bo  = (const float*)d_in[5];
    const float* W1  = (const float*)d_in[6];
    const float* b1  = (const float*)d_in[7];
    const float* W2  = (const float*)d_in[8];
    const float* b2  = (const float*)d_in[9];
    const float* g1  = (const float*)d_in[10];
    const float* be1 = (const float*)d_in[11];
    const float* g2  = (const float*)d_in[12];
    const float* be2 = (const float*)d_in[13];
    float* out = (float*)d_out;

    char* ws = (char*)d_ws;
    size_t off = 0;
    auto alloc = [&](size_t bytes) { void* p = ws + off; off += bytes; return p; };
    u16* Wq_t = (u16*)alloc((size_t)HID * HID * 2);
    u16* Wk_t = (u16*)alloc((size_t)HID * HID * 2);
    u16* Wv_t = (u16*)alloc((size_t)HID * HID * 2);
    u16* Wo_t = (u16*)alloc((size_t)HID * HID * 2);
    u16* W1_t = (u16*)alloc((size_t)DFF * HID * 2);
    u16* W2_t = (u16*)alloc((size_t)HID * DFF * 2);
    u16* h1   = (u16*)alloc((size_t)NTOK * HID * 2);   // reused as h2
    u16* Qb   = (u16*)alloc((size_t)NTOK * HID * 2);
    u16* Kb   = (u16*)alloc((size_t)NTOK * HID * 2);
    u16* Vb   = (u16*)alloc((size_t)NTOK * HID * 2);   // reused as attn_out
    u16* Vt   = (u16*)alloc((size_t)NTOK * HID * 2);
    float* x2 = (float*)alloc((size_t)NTOK * HID * 4);
    u16* ff1  = Qb;   // reuses Q/K/V/Vt region (64MB) after attention+Wo done

    // weights -> bf16 B^T
    transpose_w<<<dim3(32, 2, 16), 256, 0, stream>>>(Wq, Wq_t, HID, HD);
    transpose_w<<<dim3(32, 2, 16), 256, 0, stream>>>(Wk, Wk_t, HID, HD);
    transpose_w<<<dim3(32, 2, 16), 256, 0, stream>>>(Wv, Wv_t, HID, HD);
    transpose_w<<<dim3(32, 32, 1), 256, 0, stream>>>(Wo, Wo_t, HID, HID);
    transpose_w<<<dim3(32, 128, 1), 256, 0, stream>>>(W1, W1_t, HID, DFF);
    transpose_w<<<dim3(128, 32, 1), 256, 0, stream>>>(W2, W2_t, DFF, HID);

    // LN1
    ln_kernel<<<NTOK, 256, 0, stream>>>(x, g1, be1, h1);

    // QKV projections (Q pre-scaled by 1/sqrt(64))
    gemm_kernel<0><<<dim3(64, 8), 256, 0, stream>>>(h1, Wq_t, nullptr, Qb, nullptr, nullptr, HID, HID, 0.125f);
    gemm_kernel<0><<<dim3(64, 8), 256, 0, stream>>>(h1, Wk_t, nullptr, Kb, nullptr, nullptr, HID, HID, 1.0f);
    gemm_kernel<0><<<dim3(64, 8), 256, 0, stream>>>(h1, Wv_t, nullptr, Vb, nullptr, nullptr, HID, HID, 1.0f);

    // V -> V^T per head
    transpose_v<<<dim3(SEQ / 64, BATCH * NH), 256, 0, stream>>>(Vb, Vt);

    // flash attention (writes concat-head layout into Vb's slot)
    u16* attn_out = Vb;
    attn_kernel<<<dim3(SEQ / 64, BATCH * NH), 256, 0, stream>>>(Qb, Kb, Vt, attn_out);

    // x2 = x + attn_out @ Wo + bo
    gemm_kernel<1><<<dim3(64, 8), 256, 0, stream>>>(attn_out, Wo_t, x2, nullptr, bo, x, HID, HID, 1.f);

    // LN2
    ln_kernel<<<NTOK, 256, 0, stream>>>(x2, g2, be2, h1);

    // ff1 = relu(h2 @ W1 + b1)
    gemm_kernel<2><<<dim3(64, 32), 256, 0, stream>>>(h1, W1_t, nullptr, ff1, b1, nullptr, HID, DFF, 1.f);

    // out = x2 + ff1 @ W2 + b2
    gemm_kernel<1><<<dim3(64, 8), 256, 0, stream>>>(ff1, W2_t, out, nullptr, b2, x2, DFF, HID, 1.f);
}